// Round 11
// baseline (175.938 us; speedup 1.0000x reference)
//
#include <hip/hip_runtime.h>
#include <hip/hip_fp16.h>

#define N_NODES 50000
#define N_EDGES 800000
#define D 64

#define SLICES 100                 // edge slices per role (src/dst)
#define I4S    2000                // int4 per slice (8000 edges)
#define NI4    200000              // total int4 per role
#define NWORDS 12512               // ceil(50000/4)=12500, padded to /4
#define HBLK   200                 // histogram blocks (2 roles x 100 slices)
#define ZBLK   568                 // z = x@W blocks fused into pass 1
#define DEGZ_BLOCKS (HBLK + ZBLK)  // 768 = 256 CUs x 3 (50KB LDS/block)

typedef float vfloat2 __attribute__((ext_vector_type(2)));

// ---------------------------------------------------------------------------
// Workspace layout (bytes), ~21 MB, offsets 256-aligned:
//   [0,        4)          ctr    : int (scan counter; zeroed by pass 1)
//   [256,      400256)     meta   : int2[N_NODES]  (.x = CSR base, .y = indeg)
//   [400384,   600384)     snorm  : float[N_NODES]
//   [600576,   3800576)    ssrc   : int[N_EDGES]   src ids grouped by dst
//   [3800576,  4600576)    occ    : uchar[N_EDGES] within-slice occurrence
//   [4600832,  14610432)   partial: uint[200][NWORDS] byte hists -> prefixes
//   [14610432, 17810432)   zA     : half[N_NODES*32] x@W features  0..31
//   [17810688, 21010688)   zB     : half[N_NODES*32] x@W features 32..63
// z is UNSCALED x@W; snorm is applied per-edge in the gather (linearity).
// ---------------------------------------------------------------------------
#define CTR_OFF    0
#define META_OFF   256
#define SNORM_OFF  400384
#define SSRC_OFF   600576
#define OCC_OFF    3800576
#define PART_OFF   4600832
#define ZA_OFF     14610432
#define ZB_OFF     17810688

// ---------------------------------------------------------------------------
// Pass 1 (fused degree-histogram + z-matmul; block-role split, no cross-block
// deps). Blocks 0..199: per-slice byte-packed degree hists in LDS; dst blocks
// also record per-edge within-slice occurrence bytes. Blocks 200..767:
// z = x @ W stored fp16 (independent of everything -> overlaps the hists).
// Block 0 zeroes the scan counter.
// ---------------------------------------------------------------------------
__global__ __launch_bounds__(256) void degz_kernel(const int4* __restrict__ src4,
                                                   const int4* __restrict__ dst4,
                                                   unsigned int* __restrict__ partial,
                                                   uchar4* __restrict__ occ4,
                                                   int* __restrict__ ctr,
                                                   const float* __restrict__ x,
                                                   const float* __restrict__ W,
                                                   __half* __restrict__ zA,
                                                   __half* __restrict__ zB) {
    __shared__ unsigned int hist[NWORDS];
    int tid = threadIdx.x;

    if (blockIdx.x >= HBLK) {
        // ---- z path: z = x @ W, fp16, feature-split halves ----
        int lane = tid & 63;
        float Wreg[D];
#pragma unroll
        for (int k = 0; k < D; k++) Wreg[k] = W[k * D + lane];
        __half* zh = (lane < 32) ? zA : zB;   // uniform per half-wave
        int jl = lane & 31;
        int wave = (blockIdx.x - HBLK) * 4 + (tid >> 6);
        const int nwaves = ZBLK * 4;
        for (int n = wave; n < N_NODES; n += nwaves) {
            float hv = x[(size_t)n * D + lane];
            int hb = __float_as_int(hv);
            float p0 = 0.f, p1 = 0.f, p2 = 0.f, p3 = 0.f;
#pragma unroll
            for (int k = 0; k < D; k += 4) {
                p0 = fmaf(__int_as_float(__builtin_amdgcn_readlane(hb, k + 0)), Wreg[k + 0], p0);
                p1 = fmaf(__int_as_float(__builtin_amdgcn_readlane(hb, k + 1)), Wreg[k + 1], p1);
                p2 = fmaf(__int_as_float(__builtin_amdgcn_readlane(hb, k + 2)), Wreg[k + 2], p2);
                p3 = fmaf(__int_as_float(__builtin_amdgcn_readlane(hb, k + 3)), Wreg[k + 3], p3);
            }
            zh[(size_t)n * 32 + jl] = __float2half((p0 + p1) + (p2 + p3));
        }
        return;
    }

    // ---- histogram path (blocks 0..199; role = b&1, slice = b>>1) ----
    if (blockIdx.x == 0 && tid == 0) *ctr = 0;
    uint4* h4 = (uint4*)hist;
    for (int i = tid; i < NWORDS / 4; i += 256) h4[i] = make_uint4(0, 0, 0, 0);
    __syncthreads();

    int role  = blockIdx.x & 1;
    int slice = blockIdx.x >> 1;
    int beg = slice * I4S, end = beg + I4S;
    if (role == 0) {
        for (int i = beg + tid; i < end; i += 256) {
            int4 v = src4[i];
            atomicAdd(&hist[v.x >> 2], 1u << ((v.x & 3) * 8));
            atomicAdd(&hist[v.y >> 2], 1u << ((v.y & 3) * 8));
            atomicAdd(&hist[v.z >> 2], 1u << ((v.z & 3) * 8));
            atomicAdd(&hist[v.w >> 2], 1u << ((v.w & 3) * 8));
        }
    } else {
        for (int i = beg + tid; i < end; i += 256) {
            int4 v = dst4[i];
            unsigned int o0 = (atomicAdd(&hist[v.x >> 2], 1u << ((v.x & 3) * 8)) >> ((v.x & 3) * 8)) & 0xFFu;
            unsigned int o1 = (atomicAdd(&hist[v.y >> 2], 1u << ((v.y & 3) * 8)) >> ((v.y & 3) * 8)) & 0xFFu;
            unsigned int o2 = (atomicAdd(&hist[v.z >> 2], 1u << ((v.z & 3) * 8)) >> ((v.z & 3) * 8)) & 0xFFu;
            unsigned int o3 = (atomicAdd(&hist[v.w >> 2], 1u << ((v.w & 3) * 8)) >> ((v.w & 3) * 8)) & 0xFFu;
            occ4[i] = make_uchar4((unsigned char)o0, (unsigned char)o1,
                                  (unsigned char)o2, (unsigned char)o3);
        }
    }
    __syncthreads();

    uint4* p4 = (uint4*)(partial + (size_t)blockIdx.x * NWORDS);
    for (int i = tid; i < NWORDS / 4; i += 256) p4[i] = h4[i];
}

// ---------------------------------------------------------------------------
// Pass 2 (merge + scan, 4 threads per word): r0/r1 sum src slices 0-49/50-99;
// r2 sums + rewrites dst slices 0-49 to exclusive prefixes (start 0); r3 sums
// + register-buffers dst slices 50-99, then replays the rewrite from registers
// with start = r2's total (via shfl). Cuts the per-thread serial load chain
// 200 -> 50. Packed byte adds are carry-free (cumulative <= indeg < 255).
// Then a wave scan of per-word totals (carried by r3 lanes) -> CSR bases.
// ---------------------------------------------------------------------------
#define MSBLK 196                  // 196*256/4 = 12544 words >= 12500
__global__ __launch_bounds__(256) void merge_scan_kernel(unsigned int* __restrict__ partial,
                                                         int2* __restrict__ meta,
                                                         float* __restrict__ snorm,
                                                         int* __restrict__ ctr) {
    int lane = threadIdx.x & 63;
    int r = threadIdx.x & 3;
    int w = (blockIdx.x * blockDim.x + threadIdx.x) >> 2;
    bool act = (w < 12500);

    unsigned int buf[50];
    unsigned int acc = 0;
    if (act) {
        int isdst = (r >= 2);
        int sbase = (r & 1) ? 50 : 0;
        unsigned int* p = partial + (size_t)isdst * NWORDS
                        + (size_t)(2 * sbase) * NWORDS + w;
#pragma unroll
        for (int s = 0; s < 50; s++) {
            unsigned int v = p[(size_t)(2 * s) * NWORDS];
            buf[s] = v;
            if (r == 2) p[(size_t)(2 * s) * NWORDS] = acc;  // exclusive prefix
            acc += v;
        }
    }
    unsigned int mysum = acc;

    int wl = lane & ~3;
    unsigned int s0v = __shfl(mysum, wl);
    unsigned int s1v = __shfl(mysum, wl | 1);
    unsigned int s2v = __shfl(mysum, wl | 2);
    unsigned int s3v = __shfl(mysum, wl | 3);

    if (act && r == 3) {       // replay rewrite from registers, start = r2 total
        unsigned int* p = partial + NWORDS + (size_t)(2 * 50) * NWORDS + w;
        unsigned int a2 = s2v;
#pragma unroll
        for (int s = 0; s < 50; s++) {
            p[(size_t)(2 * s) * NWORDS] = a2;
            a2 += buf[s];
        }
    }

    unsigned int accin  = s2v + s3v;   // packed indeg  (byte-wise safe)
    unsigned int accout = s0v + s1v;   // packed outdeg (byte-wise safe)
    int d0 = accin & 0xFF, d1 = (accin >> 8) & 0xFF,
        d2 = (accin >> 16) & 0xFF, d3 = (accin >> 24) & 0xFF;
    int tsum = d0 + d1 + d2 + d3;
    int run = (act && r == 3) ? tsum : 0;
#pragma unroll
    for (int off = 1; off < 64; off <<= 1) {
        int v = __shfl_up(run, off);
        if (lane >= off) run += v;
    }
    int wtot = __shfl(run, 63);
    int wbase = 0;
    if (lane == 63) wbase = atomicAdd(ctr, wtot);
    wbase = __shfl(wbase, 63);

    if (act && r == 3) {
        int b0 = wbase + run - tsum;
        int b1 = b0 + d0, b2 = b1 + d1, b3 = b2 + d2;
        ((int4*)meta)[2 * w]     = make_int4(b0, d0, b1, d1);
        ((int4*)meta)[2 * w + 1] = make_int4(b2, d2, b3, d3);
        int o0 = accout & 0xFF, o1 = (accout >> 8) & 0xFF,
            o2 = (accout >> 16) & 0xFF, o3 = (accout >> 24) & 0xFF;
        ((float4*)snorm)[w] = make_float4(rsqrtf(fmaxf((float)o0, 1.f)),
                                          rsqrtf(fmaxf((float)o1, 1.f)),
                                          rsqrtf(fmaxf((float)o2, 1.f)),
                                          rsqrtf(fmaxf((float)o3, 1.f)));
    }
}

// ---------------------------------------------------------------------------
// Pass 3: CSR fill — fully parallel, no LDS, no atomics:
// p = meta.x + per-slice exclusive prefix byte + occurrence byte.
// ---------------------------------------------------------------------------
__global__ __launch_bounds__(256) void fill_kernel(const int4* __restrict__ src4,
                                                   const int4* __restrict__ dst4,
                                                   const uchar4* __restrict__ occ4,
                                                   const unsigned int* __restrict__ partial,
                                                   const int2* __restrict__ meta,
                                                   int* __restrict__ ssrc) {
    int tid = blockIdx.x * blockDim.x + threadIdx.x;
    if (tid >= NI4) return;
    int s = tid / I4S;
    const unsigned int* pref = partial + (size_t)(2 * s + 1) * NWORDS;
    int4 sv = src4[tid], tv = dst4[tid];
    uchar4 oc = occ4[tid];
#define FILL_ONE(T, S, O)                                                     \
    {                                                                         \
        int t = (T); int sh = (t & 3) * 8;                                    \
        int p = meta[t].x + (int)((pref[t >> 2] >> sh) & 0xFFu) + (int)(O);   \
        ssrc[p] = (S);                                                        \
    }
    FILL_ONE(tv.x, sv.x, oc.x)
    FILL_ONE(tv.y, sv.y, oc.y)
    FILL_ONE(tv.z, sv.z, oc.z)
    FILL_ONE(tv.w, sv.w, oc.w)
#undef FILL_ONE
}

// ---------------------------------------------------------------------------
// Pass 4: out[n] = rsqrt(indeg) * sum_{in-edges} snorm[src]*z[src] + b, by
// feature half (pass = blockIdx&1: XCD partition of zA/zB). Lane = (q =
// edge-of-4, c = half2 chunk): one wave-load = 4 rows of 64 B; snorm[src] is
// a broadcast 4B load per edge, applied as fma (replaces the plain add).
// shfl ^16/^32 reduce; nontemporal float2 stores.
// ---------------------------------------------------------------------------
#define GBLK 2048
__global__ __launch_bounds__(256, 8) void gather_kernel(const __half2* __restrict__ zA,
                                                        const __half2* __restrict__ zB,
                                                        const int* __restrict__ ssrc,
                                                        const int2* __restrict__ meta,
                                                        const float* __restrict__ snorm,
                                                        const float* __restrict__ bias,
                                                        float* __restrict__ out) {
    int lane = threadIdx.x & 63;
    int q = lane >> 4;
    int c = lane & 15;
    int pass = blockIdx.x & 1;         // 0 -> zA, 1 -> zB
    int pblk = blockIdx.x >> 1;
    int wave = (pblk << 2) | (threadIdx.x >> 6);
    const int nwaves = (GBLK / 2) * 4;

    float2 b2 = ((const float2*)bias)[(pass << 4) + c];
    const __half2* zcol = (pass ? zB : zA) + c;   // row stride = 16 half2

#define ACC(A, F, SN) { (A).x = fmaf((F).x, (SN), (A).x); (A).y = fmaf((F).y, (SN), (A).y); }

    for (int n = wave; n < N_NODES; n += nwaves) {
        int2 m = meta[n];
        int beg = m.x, end = m.x + m.y;
        float dn = rsqrtf(fmaxf((float)m.y, 1.0f));
        float2 a0 = make_float2(0.f, 0.f), a1 = a0, a2 = a0, a3 = a0;
        float2 a4 = a0, a5 = a0, a6 = a0, a7 = a0;
        int i = beg;
        for (; i + 32 <= end; i += 32) {   // 32 edges, 8 group-loads in flight
            int s0 = ssrc[i + q],      s1 = ssrc[i + 4 + q];
            int s2 = ssrc[i + 8 + q],  s3 = ssrc[i + 12 + q];
            int s4 = ssrc[i + 16 + q], s5 = ssrc[i + 20 + q];
            int s6 = ssrc[i + 24 + q], s7 = ssrc[i + 28 + q];
            float n0 = snorm[s0], n1 = snorm[s1], n2 = snorm[s2], n3 = snorm[s3];
            float n4 = snorm[s4], n5 = snorm[s5], n6 = snorm[s6], n7 = snorm[s7];
            float2 f0 = __half22float2(zcol[(size_t)s0 * 16]);
            float2 f1 = __half22float2(zcol[(size_t)s1 * 16]);
            float2 f2 = __half22float2(zcol[(size_t)s2 * 16]);
            float2 f3 = __half22float2(zcol[(size_t)s3 * 16]);
            float2 f4 = __half22float2(zcol[(size_t)s4 * 16]);
            float2 f5 = __half22float2(zcol[(size_t)s5 * 16]);
            float2 f6 = __half22float2(zcol[(size_t)s6 * 16]);
            float2 f7 = __half22float2(zcol[(size_t)s7 * 16]);
            ACC(a0, f0, n0) ACC(a1, f1, n1) ACC(a2, f2, n2) ACC(a3, f3, n3)
            ACC(a4, f4, n4) ACC(a5, f5, n5) ACC(a6, f6, n6) ACC(a7, f7, n7)
        }
        for (; i + 16 <= end; i += 16) {   // 16 edges, 4 loads
            int s0 = ssrc[i + q],      s1 = ssrc[i + 4 + q];
            int s2 = ssrc[i + 8 + q],  s3 = ssrc[i + 12 + q];
            float n0 = snorm[s0], n1 = snorm[s1], n2 = snorm[s2], n3 = snorm[s3];
            float2 f0 = __half22float2(zcol[(size_t)s0 * 16]);
            float2 f1 = __half22float2(zcol[(size_t)s1 * 16]);
            float2 f2 = __half22float2(zcol[(size_t)s2 * 16]);
            float2 f3 = __half22float2(zcol[(size_t)s3 * 16]);
            ACC(a0, f0, n0) ACC(a1, f1, n1) ACC(a2, f2, n2) ACC(a3, f3, n3)
        }
        for (; i + 4 <= end; i += 4) {     // 4-edge groups
            int s = ssrc[i + q];
            float sn = snorm[s];
            float2 f = __half22float2(zcol[(size_t)s * 16]);
            ACC(a0, f, sn)
        }
        int rem = end - i;                 // tail < 4 edges
        if (q < rem) {
            int s = ssrc[i + q];
            float sn = snorm[s];
            float2 f = __half22float2(zcol[(size_t)s * 16]);
            ACC(a1, f, sn)
        }
        float2 t;
        t.x = ((a0.x + a1.x) + (a2.x + a3.x)) + ((a4.x + a5.x) + (a6.x + a7.x));
        t.y = ((a0.y + a1.y) + (a2.y + a3.y)) + ((a4.y + a5.y) + (a6.y + a7.y));
        t.x += __shfl(t.x, lane ^ 16); t.y += __shfl(t.y, lane ^ 16);
        t.x += __shfl(t.x, lane ^ 32); t.y += __shfl(t.y, lane ^ 32);
        if (q == 0) {
            vfloat2 o;
            o.x = fmaf(t.x, dn, b2.x);
            o.y = fmaf(t.y, dn, b2.y);
            __builtin_nontemporal_store(o, (vfloat2*)(out + (size_t)n * D + (pass << 5)) + c);
        }
    }
#undef ACC
}

extern "C" void kernel_launch(void* const* d_in, const int* in_sizes, int n_in,
                              void* d_out, int out_size, void* d_ws, size_t ws_size,
                              hipStream_t stream) {
    const float* x   = (const float*)d_in[0];
    const int*   src = (const int*)d_in[1];
    const int*   dst = (const int*)d_in[2];
    const float* W   = (const float*)d_in[3];
    const float* b   = (const float*)d_in[4];
    float* out = (float*)d_out;

    char* ws = (char*)d_ws;
    int*          ctr   = (int*)(ws + CTR_OFF);
    int2*         meta  = (int2*)(ws + META_OFF);
    float*        snorm = (float*)(ws + SNORM_OFF);
    int*          ssrc  = (int*)(ws + SSRC_OFF);
    uchar4*       occ4  = (uchar4*)(ws + OCC_OFF);
    unsigned int* part  = (unsigned int*)(ws + PART_OFF);
    __half*       zA    = (__half*)(ws + ZA_OFF);
    __half*       zB    = (__half*)(ws + ZB_OFF);

    const int4* src4 = (const int4*)src;
    const int4* dst4 = (const int4*)dst;

    degz_kernel<<<DEGZ_BLOCKS, 256, 0, stream>>>(src4, dst4, part, occ4, ctr,
                                                 x, W, zA, zB);
    merge_scan_kernel<<<MSBLK, 256, 0, stream>>>(part, meta, snorm, ctr);
    fill_kernel<<<(NI4 + 255) / 256, 256, 0, stream>>>(src4, dst4, occ4, part,
                                                       meta, ssrc);
    gather_kernel<<<GBLK, 256, 0, stream>>>((const __half2*)zA, (const __half2*)zB,
                                            ssrc, meta, snorm, b, out);
}

// Round 12
// 148.955 us; speedup vs baseline: 1.1811x; 1.1811x over previous
//
#include <hip/hip_runtime.h>
#include <hip/hip_fp16.h>

#define N_NODES 50000
#define N_EDGES 800000
#define D 64

#define SLICES 100                 // edge slices per role (src/dst)
#define I4S    2000                // int4 per slice (8000 edges)
#define NI4    200000              // total int4 per role
#define NWORDS 12512               // ceil(50000/4)=12500, padded to /4

typedef float vfloat2 __attribute__((ext_vector_type(2)));

// ---------------------------------------------------------------------------
// Workspace layout (bytes), ~21.2 MB, offsets 256-aligned:
//   [0,        64)         ctr    : int (scan counter; zeroed by degree pass)
//   [256,      200256)     base   : int[N_NODES]
//   [200320,   400320)     rend   : int[N_NODES]
//   [400384,   600384)     snorm  : float[N_NODES]
//   [600448,   800448)     dnorm  : float[N_NODES]
//   [800512,   4000512)    ssrc   : int[N_EDGES]   src ids grouped by dst
//   [4000768,  4800768)    occ    : uchar[N_EDGES] within-slice occurrence
//   [4800768,  14810368)   partial: uint[200][NWORDS] byte hists -> prefixes
//   [14810368, 18010368)   yA     : half[N_NODES*32] features  0..31 (3.2 MB)
//   [18010624, 21210624)   yB     : half[N_NODES*32] features 32..63 (3.2 MB)
// Each y half fits a 4 MB per-XCD L2 — the gather partitions passes by XCD.
// ---------------------------------------------------------------------------
#define CTR_OFF    0
#define BASE_OFF   256
#define END_OFF    200320
#define SNORM_OFF  400384
#define DNORM_OFF  600448
#define SSRC_OFF   800512
#define OCC_OFF    4000768
#define PART_OFF   4800768
#define YA_OFF     14810368
#define YB_OFF     18010624

// ---------------------------------------------------------------------------
// Pass 1: per-slice byte-packed degree histograms in LDS (no fabric atomics).
// dst-role blocks also record each edge's within-slice occurrence byte
// (the atomicAdd return) into occ[] so the fill pass needs no histogram.
// Block b: role = b&1 (0=src/outdeg, 1=dst/indeg), slice = b>>1.
// Block 0 zeroes the scan counter (replaces the memset dispatch).
// ---------------------------------------------------------------------------
__global__ __launch_bounds__(256) void degree_occ_kernel(const int4* __restrict__ src4,
                                                         const int4* __restrict__ dst4,
                                                         unsigned int* __restrict__ partial,
                                                         uchar4* __restrict__ occ4,
                                                         int* __restrict__ ctr) {
    __shared__ unsigned int hist[NWORDS];
    int tid = threadIdx.x;
    if (blockIdx.x == 0 && tid == 0) *ctr = 0;
    uint4* h4 = (uint4*)hist;
    for (int i = tid; i < NWORDS / 4; i += 256) h4[i] = make_uint4(0, 0, 0, 0);
    __syncthreads();

    int role  = blockIdx.x & 1;
    int slice = blockIdx.x >> 1;
    int beg = slice * I4S, end = beg + I4S;
    if (role == 0) {
        for (int i = beg + tid; i < end; i += 256) {
            int4 v = src4[i];
            atomicAdd(&hist[v.x >> 2], 1u << ((v.x & 3) * 8));
            atomicAdd(&hist[v.y >> 2], 1u << ((v.y & 3) * 8));
            atomicAdd(&hist[v.z >> 2], 1u << ((v.z & 3) * 8));
            atomicAdd(&hist[v.w >> 2], 1u << ((v.w & 3) * 8));
        }
    } else {
        for (int i = beg + tid; i < end; i += 256) {
            int4 v = dst4[i];
            unsigned int o0 = (atomicAdd(&hist[v.x >> 2], 1u << ((v.x & 3) * 8)) >> ((v.x & 3) * 8)) & 0xFFu;
            unsigned int o1 = (atomicAdd(&hist[v.y >> 2], 1u << ((v.y & 3) * 8)) >> ((v.y & 3) * 8)) & 0xFFu;
            unsigned int o2 = (atomicAdd(&hist[v.z >> 2], 1u << ((v.z & 3) * 8)) >> ((v.z & 3) * 8)) & 0xFFu;
            unsigned int o3 = (atomicAdd(&hist[v.w >> 2], 1u << ((v.w & 3) * 8)) >> ((v.w & 3) * 8)) & 0xFFu;
            occ4[i] = make_uchar4((unsigned char)o0, (unsigned char)o1,
                                  (unsigned char)o2, (unsigned char)o3);
        }
    }
    __syncthreads();

    uint4* p4 = (uint4*)(partial + (size_t)blockIdx.x * NWORDS);
    for (int i = tid; i < NWORDS / 4; i += 256) p4[i] = h4[i];
}

// Pass 2 (fused merge + scan): thread per word (4 nodes). Sums packed degrees
// over all slices, rewrites dst-role partials in place to per-slice EXCLUSIVE
// prefixes (byte adds; cumulative <= indeg < 255, no carry), then wave-scans
// the 4-node sums for CSR bases; writes all node arrays as int4/float4.
__global__ __launch_bounds__(256) void merge_scan_kernel(unsigned int* __restrict__ partial,
                                                         int* __restrict__ base,
                                                         int* __restrict__ rend,
                                                         float* __restrict__ snorm,
                                                         float* __restrict__ dnorm,
                                                         int* __restrict__ ctr) {
    int w = blockIdx.x * blockDim.x + threadIdx.x;
    int lane = threadIdx.x & 63;
    unsigned int accin = 0, accout = 0;
    if (w < 12500) {
        unsigned int* po = partial + w;            // src role: slot 2s
        unsigned int* pd = partial + NWORDS + w;   // dst role: slot 2s+1
#pragma unroll 4
        for (int s = 0; s < SLICES; s++) {
            size_t off = (size_t)(2 * s) * NWORDS;
            accout += po[off];
            unsigned int v = pd[off];
            pd[off] = accin;                       // exclusive prefix before slice s
            accin += v;
        }
    }
    int d0 = accin & 0xFF, d1 = (accin >> 8) & 0xFF,
        d2 = (accin >> 16) & 0xFF, d3 = (accin >> 24) & 0xFF;
    int tsum = d0 + d1 + d2 + d3;
    int run = tsum;  // inclusive wave scan of per-thread totals
#pragma unroll
    for (int off = 1; off < 64; off <<= 1) {
        int v = __shfl_up(run, off);
        if (lane >= off) run += v;
    }
    int wtot = __shfl(run, 63);
    int wbase = 0;
    if (lane == 63) wbase = atomicAdd(ctr, wtot);
    wbase = __shfl(wbase, 63);
    if (w < 12500) {
        int b0 = wbase + run - tsum;
        int b1 = b0 + d0, b2 = b1 + d1, b3 = b2 + d2;
        ((int4*)base)[w] = make_int4(b0, b1, b2, b3);
        ((int4*)rend)[w] = make_int4(b1, b2, b3, b3 + d3);
        ((float4*)dnorm)[w] = make_float4(rsqrtf(fmaxf((float)d0, 1.f)),
                                          rsqrtf(fmaxf((float)d1, 1.f)),
                                          rsqrtf(fmaxf((float)d2, 1.f)),
                                          rsqrtf(fmaxf((float)d3, 1.f)));
        int o0 = accout & 0xFF, o1 = (accout >> 8) & 0xFF,
            o2 = (accout >> 16) & 0xFF, o3 = (accout >> 24) & 0xFF;
        ((float4*)snorm)[w] = make_float4(rsqrtf(fmaxf((float)o0, 1.f)),
                                          rsqrtf(fmaxf((float)o1, 1.f)),
                                          rsqrtf(fmaxf((float)o2, 1.f)),
                                          rsqrtf(fmaxf((float)o3, 1.f)));
    }
}

// Pass 3 (fused fill + y): two independent streaming phases in one dispatch.
// Fill: fully parallel, no LDS, no atomics — p = base[t] + slice prefix + occ.
// Y:    y = (x * snorm) @ W stored fp16, split into two feature-half arrays
//       yA (features 0..31) / yB (32..63), each 3.2 MB (per-XCD-L2-sized).
#define FYBLK 1024
__global__ __launch_bounds__(256, 4) void filly_kernel(const int4* __restrict__ src4,
                                                       const int4* __restrict__ dst4,
                                                       const uchar4* __restrict__ occ4,
                                                       const unsigned int* __restrict__ partial,
                                                       const int* __restrict__ base,
                                                       int* __restrict__ ssrc,
                                                       const float* __restrict__ x,
                                                       const float* __restrict__ snorm,
                                                       const float* __restrict__ W,
                                                       __half* __restrict__ yA,
                                                       __half* __restrict__ yB) {
    int tid = blockIdx.x * blockDim.x + threadIdx.x;
    int lane = threadIdx.x & 63;

    if (tid < NI4) {
        int s = tid / I4S;
        const unsigned int* pref = partial + (size_t)(2 * s + 1) * NWORDS;
        int4 sv = src4[tid], tv = dst4[tid];
        uchar4 oc = occ4[tid];
#define FILL_ONE(T, S, O)                                                     \
        {                                                                     \
            int t = (T); int sh = (t & 3) * 8;                                \
            int p = base[t] + (int)((pref[t >> 2] >> sh) & 0xFFu) + (int)(O); \
            ssrc[p] = (S);                                                    \
        }
        FILL_ONE(tv.x, sv.x, oc.x)
        FILL_ONE(tv.y, sv.y, oc.y)
        FILL_ONE(tv.z, sv.z, oc.z)
        FILL_ONE(tv.w, sv.w, oc.w)
#undef FILL_ONE
    }

    float Wreg[D];
#pragma unroll
    for (int k = 0; k < D; k++) Wreg[k] = W[k * D + lane];
    __half* yh = (lane < 32) ? yA : yB;   // uniform per half-wave
    int jl = lane & 31;
    int wave = tid >> 6;
    const int nwaves = FYBLK * 4;
    for (int n = wave; n < N_NODES; n += nwaves) {
        float hv = x[(size_t)n * D + lane] * snorm[n];
        int hb = __float_as_int(hv);
        float p0 = 0.f, p1 = 0.f, p2 = 0.f, p3 = 0.f;
#pragma unroll
        for (int k = 0; k < D; k += 4) {
            p0 = fmaf(__int_as_float(__builtin_amdgcn_readlane(hb, k + 0)), Wreg[k + 0], p0);
            p1 = fmaf(__int_as_float(__builtin_amdgcn_readlane(hb, k + 1)), Wreg[k + 1], p1);
            p2 = fmaf(__int_as_float(__builtin_amdgcn_readlane(hb, k + 2)), Wreg[k + 2], p2);
            p3 = fmaf(__int_as_float(__builtin_amdgcn_readlane(hb, k + 3)), Wreg[k + 3], p3);
        }
        yh[(size_t)n * 32 + jl] = __float2half((p0 + p1) + (p2 + p3));
    }
}

// Pass 4: out[n] = dnorm[n] * sum_{in-edges} y[src] + b, split by feature half.
// pass = blockIdx&1: with round-robin block->XCD dispatch, even XCDs only read
// yA and odd XCDs only yB — each 3.2 MB array stays resident in its XCDs' 4 MB
// L2. Lane = (q = edge-in-group-of-4, c = half2 chunk): one wave-load = 4 rows
// of 64 B. shfl ^16/^32 reduce; q==0 writes coalesced nontemporal float2.
#define GBLK 2048
__global__ __launch_bounds__(256, 8) void gather_kernel(const __half2* __restrict__ yA,
                                                        const __half2* __restrict__ yB,
                                                        const int* __restrict__ ssrc,
                                                        const int* __restrict__ base,
                                                        const int* __restrict__ rend,
                                                        const float* __restrict__ dnorm,
                                                        const float* __restrict__ bias,
                                                        float* __restrict__ out) {
    int lane = threadIdx.x & 63;
    int q = lane >> 4;                 // which edge of the group of 4
    int c = lane & 15;                 // half2 chunk: features {2c, 2c+1} of the half
    int pass = blockIdx.x & 1;         // 0 -> yA (features 0..31), 1 -> yB (32..63)
    int pblk = blockIdx.x >> 1;
    int wave = (pblk << 2) | (threadIdx.x >> 6);
    const int nwaves = (GBLK / 2) * 4;

    float2 b2 = ((const float2*)bias)[(pass << 4) + c];
    const __half2* ycol = (pass ? yB : yA) + c;   // row stride = 16 half2

#define ACC(A, F) { (A).x += (F).x; (A).y += (F).y; }

    for (int n = wave; n < N_NODES; n += nwaves) {
        int beg = base[n], end = rend[n];
        float dn = dnorm[n];
        float2 a0 = make_float2(0.f, 0.f), a1 = a0, a2 = a0, a3 = a0;
        int i = beg;
        for (; i + 16 <= end; i += 16) {   // 16 edges, 4 row-group loads in flight
            int s0 = ssrc[i + q],      s1 = ssrc[i + 4 + q];
            int s2 = ssrc[i + 8 + q],  s3 = ssrc[i + 12 + q];
            float2 f0 = __half22float2(ycol[(size_t)s0 * 16]);
            float2 f1 = __half22float2(ycol[(size_t)s1 * 16]);
            float2 f2 = __half22float2(ycol[(size_t)s2 * 16]);
            float2 f3 = __half22float2(ycol[(size_t)s3 * 16]);
            ACC(a0, f0) ACC(a1, f1) ACC(a2, f2) ACC(a3, f3)
        }
        for (; i + 4 <= end; i += 4) {     // 4-edge groups
            int s = ssrc[i + q];
            float2 f = __half22float2(ycol[(size_t)s * 16]);
            ACC(a0, f)
        }
        int rem = end - i;                 // tail < 4 edges
        if (q < rem) {
            int s = ssrc[i + q];
            float2 f = __half22float2(ycol[(size_t)s * 16]);
            ACC(a1, f)
        }
        float2 t;
        t.x = (a0.x + a1.x) + (a2.x + a3.x);
        t.y = (a0.y + a1.y) + (a2.y + a3.y);
        t.x += __shfl(t.x, lane ^ 16); t.y += __shfl(t.y, lane ^ 16);
        t.x += __shfl(t.x, lane ^ 32); t.y += __shfl(t.y, lane ^ 32);
        if (q == 0) {
            vfloat2 o;
            o.x = fmaf(t.x, dn, b2.x);
            o.y = fmaf(t.y, dn, b2.y);
            __builtin_nontemporal_store(o, (vfloat2*)(out + (size_t)n * D + (pass << 5)) + c);
        }
    }
#undef ACC
}

extern "C" void kernel_launch(void* const* d_in, const int* in_sizes, int n_in,
                              void* d_out, int out_size, void* d_ws, size_t ws_size,
                              hipStream_t stream) {
    const float* x   = (const float*)d_in[0];
    const int*   src = (const int*)d_in[1];
    const int*   dst = (const int*)d_in[2];
    const float* W   = (const float*)d_in[3];
    const float* b   = (const float*)d_in[4];
    float* out = (float*)d_out;

    char* ws = (char*)d_ws;
    int*          ctr   = (int*)(ws + CTR_OFF);
    int*          base  = (int*)(ws + BASE_OFF);
    int*          rend  = (int*)(ws + END_OFF);
    float*        snorm = (float*)(ws + SNORM_OFF);
    float*        dnorm = (float*)(ws + DNORM_OFF);
    int*          ssrc  = (int*)(ws + SSRC_OFF);
    uchar4*       occ4  = (uchar4*)(ws + OCC_OFF);
    unsigned int* part  = (unsigned int*)(ws + PART_OFF);
    __half*       yA    = (__half*)(ws + YA_OFF);
    __half*       yB    = (__half*)(ws + YB_OFF);

    const int4* src4 = (const int4*)src;
    const int4* dst4 = (const int4*)dst;

    degree_occ_kernel<<<2 * SLICES, 256, 0, stream>>>(src4, dst4, part, occ4, ctr);
    merge_scan_kernel<<<(12500 + 255) / 256, 256, 0, stream>>>(part, base, rend,
                                                               snorm, dnorm, ctr);
    filly_kernel<<<FYBLK, 256, 0, stream>>>(src4, dst4, occ4, part, base, ssrc,
                                            x, snorm, W, yA, yB);
    gather_kernel<<<GBLK, 256, 0, stream>>>((const __half2*)yA, (const __half2*)yB,
                                            ssrc, base, rend, dnorm, b, out);
}